// Round 8
// baseline (339.241 us; speedup 1.0000x reference)
//
#include <hip/hip_runtime.h>
#include <hip/hip_bf16.h>
#include <math.h>

#define HW   36864        // 192*192
#define BHW  73728        // 2*HW

typedef float f32x4 __attribute__((ext_vector_type(4)));
typedef float f32x2 __attribute__((ext_vector_type(2)));
typedef short short8 __attribute__((ext_vector_type(8)));

__device__ __forceinline__ unsigned f2bf(float f) {        // fp32 -> bf16 bits, RNE
    unsigned u = __float_as_uint(f);
    return (u + 0x7fffu + ((u >> 16) & 1u)) >> 16;
}
__device__ __forceinline__ float bf2f(unsigned short s) {  // bf16 bits -> fp32
    return __uint_as_float(((unsigned)s) << 16);
}
// tanh-approx gelu; <1e-3 abs dev from erf-gelu, ~7 instr vs ~25 for erff.
__device__ __forceinline__ float gelu_fast(float x) {
    float y = 1.5957691216057308f * fmaf(0.044715f * x * x, x, x);
    return x / (1.0f + __expf(-y));
}

// ---------------------------------------------------------------- weight prep
// fc1 weights/bias PAIRED v2: weight row j -> source channel (j>>5)*16 + (j&15),
// u/v = (j>>4)&1 -> u and v of one channel land in nt=0/1 of the same lane.
__global__ __launch_bounds__(256)
void wconv_kernel(const float* __restrict__ w1, const float* __restrict__ w2,
                  const float* __restrict__ wq, const float* __restrict__ wp,
                  const float* __restrict__ wf1, const float* __restrict__ wf2,
                  const float* __restrict__ dww, const float* __restrict__ fb1,
                  ushort* __restrict__ o1, ushort* __restrict__ o2, ushort* __restrict__ oq,
                  ushort* __restrict__ op, ushort* __restrict__ of1, ushort* __restrict__ of2,
                  float* __restrict__ dwt, float* __restrict__ bg)
{
    int i = blockIdx.x * 256 + threadIdx.x;
    if      (i <  65536) o1 [i         ] = (ushort)f2bf(w1 [i         ]);
    else if (i <  98304) o2 [i -  65536] = (ushort)f2bf(w2 [i -  65536]);
    else if (i < 147456) oq [i -  98304] = (ushort)f2bf(wq [i -  98304]);
    else if (i < 163840) op [i - 147456] = (ushort)f2bf(wp [i - 147456]);
    else if (i < 229376) {
        int j = i - 163840;            // paired fc1 v2: col=j>>7, k=j&127
        int col = j >> 7, k = j & 127;
        int src = ((col >> 4) & 1) * 256 + ((col >> 5) << 4) + (col & 15);
        of1[j] = (ushort)f2bf(wf1[(size_t)src * 128 + k]);
    }
    else if (i < 262144) of2[i - 229376] = (ushort)f2bf(wf2[i - 229376]);
    else if (i < 266752) {
        int j = i - 262144;            // j = tap*512 + c
        int tap = j >> 9, c = j & 511;
        dwt[j] = dww[c * 9 + tap];
    }
    else if (i < 267264) {
        int j = i - 266752;            // paired fc1 bias v2
        bg[j] = fb1[((j >> 4) & 1) * 256 + ((j >> 5) << 4) + (j & 15)];
    }
}

// ---------------------------------------------------------------- rmsnorm (NCHW fp32 -> pixel-major bf16)
// 64 pixels/block; the 4 waves split the 128-channel reduction (32 ch each).
__global__ __launch_bounds__(256)
void rmsnorm_t_kernel(const float* __restrict__ src, const float* __restrict__ s,
                      const float* __restrict__ bi, __hip_bfloat16* __restrict__ dst)
{
    __shared__ float sPar[4][64];
    __shared__ float sInv[64];
    int t = threadIdx.x, lane = t & 63, wv = t >> 6;
    int P = blockIdx.x * 64 + lane;                  // pixel id in [0, BHW)
    int b = P / HW, pp = P - b * HW;
    const float* xb = src + (size_t)b * 128 * HW + pp;
    float v[32];
    float ss = 0.f;
#pragma unroll
    for (int i = 0; i < 32; ++i) {
        float x = xb[(size_t)(wv * 32 + i) * HW];
        v[i] = x;
        ss = fmaf(x, x, ss);
    }
    sPar[wv][lane] = ss;
    __syncthreads();
    if (t < 64) {
        float tot = sPar[0][t] + sPar[1][t] + sPar[2][t] + sPar[3][t];
        sInv[t] = 1.0f / sqrtf(tot * 0.0078125f + 1e-6f);
    }
    __syncthreads();
    float inv = sInv[lane];
    unsigned* drow = (unsigned*)(dst + (size_t)P * 128) + wv * 16;
#pragma unroll
    for (int i = 0; i < 32; i += 2) {
        int c = wv * 32 + i;
        float v0 = fmaf(s[c]     * v[i],     inv, bi[c]);
        float v1 = fmaf(s[c + 1] * v[i + 1], inv, bi[c + 1]);
        drow[i >> 1] = f2bf(v0) | (f2bf(v1) << 16);
    }
}

// ---------------------------------------------------------------- MFMA GEMM, 64x128 tile
// Full-K single-stage staging; ONE barrier, then all MFMAs.
// MODE 0: store bf16 pixel-major (BHW,N). MODE 2: paired-v2 u/v in nt=0/1 -> u*gelu(v).
template<int K, int MODE>
__global__ __launch_bounds__(256, 3)
void gemm_kernel(const __hip_bfloat16* __restrict__ Abf, const __hip_bfloat16* __restrict__ Wbf,
                 const float* __restrict__ bias, int N,
                 __hip_bfloat16* __restrict__ outb)
{
    constexpr int STEPS = K / 32;
    __shared__ __align__(16) short smem[(64 + 128) * K];   // K=128: 48KB
    short* sA = smem;                 // [STEPS][64 rows][32]
    short* sB = smem + 64 * K;        // [STEPS][128 rows][32]

    const short* A = (const short*)Abf;
    const short* W = (const short*)Wbf;

    int t = threadIdx.x;
    int lane = t & 63, wv = t >> 6;
    int m0 = blockIdx.x * 64;
    int n0 = blockIdx.y * 128;
    int q = lane >> 4, r16 = lane & 15;

    {   // stage entire K panel (issued before acc init so bias-load latency overlaps)
        int lr = lane >> 2, lk = lane & 3;
#pragma unroll
        for (int st = 0; st < STEPS; ++st) {
            int rowA = wv * 16 + lr;
            int kcA = lk ^ ((rowA >> 1) & 3);
            const short* ga = A + (size_t)(m0 + rowA) * K + st * 32 + kcA * 8;
            __builtin_amdgcn_global_load_lds((const __attribute__((address_space(1))) void*)ga,
                                             (__attribute__((address_space(3))) void*)(sA + st * 2048 + wv * 512), 16, 0, 0);
#pragma unroll
            for (int i = 0; i < 2; ++i) {
                int rb = wv * 32 + i * 16;
                int rowB = rb + lr;
                int kcB = lk ^ ((rowB >> 1) & 3);
                const short* gb = W + (size_t)(n0 + rowB) * K + st * 32 + kcB * 8;
                __builtin_amdgcn_global_load_lds((const __attribute__((address_space(1))) void*)gb,
                                                 (__attribute__((address_space(3))) void*)(sB + st * 4096 + rb * 32), 16, 0, 0);
            }
        }
    }

    f32x4 acc[4][2];
#pragma unroll
    for (int nt = 0; nt < 2; ++nt) {
        float bv = bias[n0 + wv * 32 + nt * 16 + r16];
#pragma unroll
        for (int mt = 0; mt < 4; ++mt) acc[mt][nt] = (f32x4){bv, bv, bv, bv};
    }
    __syncthreads();

#pragma unroll
    for (int st = 0; st < STEPS; ++st) {
        short8 af[4], bf[2];
#pragma unroll
        for (int mt = 0; mt < 4; ++mt) {
            int r = mt * 16 + r16;
            af[mt] = *(const short8*)(sA + st * 2048 + (r * 4 + (q ^ ((r >> 1) & 3))) * 8);
        }
#pragma unroll
        for (int nt = 0; nt < 2; ++nt) {
            int r = wv * 32 + nt * 16 + r16;
            bf[nt] = *(const short8*)(sB + st * 4096 + (r * 4 + (q ^ ((r >> 1) & 3))) * 8);
        }
#pragma unroll
        for (int mt = 0; mt < 4; ++mt)
#pragma unroll
            for (int nt = 0; nt < 2; ++nt)
                acc[mt][nt] = __builtin_amdgcn_mfma_f32_16x16x32_bf16(af[mt], bf[nt], acc[mt][nt], 0, 0, 0);
    }

    if constexpr (MODE == 0) {
        ushort* ob = (ushort*)outb;
#pragma unroll
        for (int mt = 0; mt < 4; ++mt) {
            int row0 = m0 + mt * 16 + q * 4;
#pragma unroll
            for (int nt = 0; nt < 2; ++nt) {
                int col = n0 + wv * 32 + nt * 16 + r16;
#pragma unroll
                for (int rg = 0; rg < 4; ++rg)
                    ob[(size_t)(row0 + rg) * N + col] = (ushort)f2bf(acc[mt][nt][rg]);
            }
        }
    } else {   // MODE 2, paired-v2: nt=0 holds u, nt=1 holds v of channel ch
        ushort* ob = (ushort*)outb;
        int ch = (n0 >> 1) + wv * 16 + r16;
#pragma unroll
        for (int mt = 0; mt < 4; ++mt) {
            int row0 = m0 + mt * 16 + q * 4;
#pragma unroll
            for (int rg = 0; rg < 4; ++rg) {
                float g = acc[mt][0][rg] * gelu_fast(acc[mt][1][rg]);
                ob[(size_t)(row0 + rg) * 256 + ch] = (ushort)f2bf(g);
            }
        }
    }
}

// ---------------------------------------------------------------- MFMA GEMM, N=128, 64-row tile
// Full-panel staging, processed in K/128 half-panels reusing 48KB of LDS.
template<int K, bool RMS>
__global__ __launch_bounds__(256, 3)
void gemm_n128_kernel(const __hip_bfloat16* __restrict__ Abf, const __hip_bfloat16* __restrict__ Wbf,
                      const float* __restrict__ bias,
                      const float* __restrict__ rsrc, float* __restrict__ rdst,
                      const float* __restrict__ scale,
                      const float* __restrict__ rms_s, const float* __restrict__ rms_b,
                      __hip_bfloat16* __restrict__ xn)
{
    constexpr int NH = K / 128;
    __shared__ __align__(16) char smem[49152];
    short* sA = (short*)smem;                 // [4][64 rows][32] = 16KB
    short* sB = sA + 8192;                    // [4][128 rows][32] = 32KB
    float* sEp = (float*)smem;                // [128 ch][68 px] = 34816 (overlays staging)
    float* sPar = (float*)(smem + 34816);     // RMS: [64 px][17]
    float* sInv = (float*)(smem + 39168);     // RMS: [64 px]

    const short* A = (const short*)Abf;
    const short* W = (const short*)Wbf;

    int t = threadIdx.x;
    int lane = t & 63, wv = t >> 6;
    int m0 = blockIdx.x * 64;
    int q = lane >> 4, r16 = lane & 15;

    f32x4 acc[4][2];
#pragma unroll
    for (int nt = 0; nt < 2; ++nt) {
        float bv = bias[wv * 32 + nt * 16 + r16];
#pragma unroll
        for (int mt = 0; mt < 4; ++mt) acc[mt][nt] = (f32x4){bv, bv, bv, bv};
    }

#pragma unroll
    for (int h = 0; h < NH; ++h) {
        if (h) __syncthreads();               // prev half's ds_reads done before overwrite
        {   // stage half panel (4 K-steps)
            int lr = lane >> 2, lk = lane & 3;
#pragma unroll
            for (int st = 0; st < 4; ++st) {
                int kk = h * 128 + st * 32;
                int rowA = wv * 16 + lr;
                int kcA = lk ^ ((rowA >> 1) & 3);
                const short* ga = A + (size_t)(m0 + rowA) * K + kk + kcA * 8;
                __builtin_amdgcn_global_load_lds((const __attribute__((address_space(1))) void*)ga,
                                                 (__attribute__((address_space(3))) void*)(sA + st * 2048 + wv * 512), 16, 0, 0);
#pragma unroll
                for (int i = 0; i < 2; ++i) {
                    int rb = wv * 32 + i * 16;
                    int rowB = rb + lr;
                    int kcB = lk ^ ((rowB >> 1) & 3);
                    const short* gb = W + (size_t)rowB * K + kk + kcB * 8;
                    __builtin_amdgcn_global_load_lds((const __attribute__((address_space(1))) void*)gb,
                                                     (__attribute__((address_space(3))) void*)(sB + st * 4096 + rb * 32), 16, 0, 0);
                }
            }
        }
        __syncthreads();

#pragma unroll
        for (int st = 0; st < 4; ++st) {
            short8 af[4], bf[2];
#pragma unroll
            for (int mt = 0; mt < 4; ++mt) {
                int r = mt * 16 + r16;
                af[mt] = *(const short8*)(sA + st * 2048 + (r * 4 + (q ^ ((r >> 1) & 3))) * 8);
            }
#pragma unroll
            for (int nt = 0; nt < 2; ++nt) {
                int r = wv * 32 + nt * 16 + r16;
                bf[nt] = *(const short8*)(sB + st * 4096 + (r * 4 + (q ^ ((r >> 1) & 3))) * 8);
            }
#pragma unroll
            for (int mt = 0; mt < 4; ++mt)
#pragma unroll
                for (int nt = 0; nt < 2; ++nt)
                    acc[mt][nt] = __builtin_amdgcn_mfma_f32_16x16x32_bf16(af[mt], bf[nt], acc[mt][nt], 0, 0, 0);
        }
    }
    __syncthreads();   // staging reads done before sEp overlay

    // single-pass epilogue: all 4 waves write their C fragments
#pragma unroll
    for (int mt = 0; mt < 4; ++mt)
#pragma unroll
        for (int nt = 0; nt < 2; ++nt) {
            int c = wv * 32 + nt * 16 + r16;
            int px = mt * 16 + q * 4;
#pragma unroll
            for (int rg = 0; rg < 4; ++rg)
                sEp[c * 68 + px + rg] = acc[mt][nt][rg];
        }
    __syncthreads();

    int c16 = t >> 4, l16 = t & 15;
    int p0 = m0 + l16 * 4;
    int b = p0 / HW, pp = p0 - b * HW;
    float sc = scale[0];
    f32x4 ov[8];
    f32x4 ps = (f32x4){0.f, 0.f, 0.f, 0.f};
#pragma unroll
    for (int i = 0; i < 8; ++i) {
        int c = c16 + i * 16;
        f32x4 v = *(const f32x4*)&sEp[c * 68 + l16 * 4];
        size_t gi = (size_t)(b * 128 + c) * HW + pp;
        f32x4 r = *(const f32x4*)&rsrc[gi];
        f32x4 o = r + sc * v;
        *(f32x4*)&rdst[gi] = o;
        if constexpr (RMS) {
            ov[i] = o;
#pragma unroll
            for (int rg = 0; rg < 4; ++rg) ps[rg] = fmaf(o[rg], o[rg], ps[rg]);
        }
    }
    if constexpr (RMS) {
#pragma unroll
        for (int rg = 0; rg < 4; ++rg) sPar[(l16 * 4 + rg) * 17 + c16] = ps[rg];
        __syncthreads();               // also fences sEp reads before sXn overlay
        if (t < 64) {
            float ssum = 0.f;
#pragma unroll
            for (int j = 0; j < 16; ++j) ssum += sPar[t * 17 + j];
            sInv[t] = 1.0f / sqrtf(ssum * 0.0078125f + 1e-6f);
        }
        __syncthreads();
        float iv[4];
#pragma unroll
        for (int rg = 0; rg < 4; ++rg) iv[rg] = sInv[l16 * 4 + rg];
        ushort* sXn = (ushort*)smem;   // overlay dead sEp: [64 px][132 ch-pad]
#pragma unroll
        for (int i = 0; i < 8; ++i) {
            int c = c16 + i * 16;
            float scs = rms_s[c], bcs = rms_b[c];
#pragma unroll
            for (int rg = 0; rg < 4; ++rg)
                sXn[(l16 * 4 + rg) * 132 + c] = (ushort)f2bf(fmaf(scs * ov[i][rg], iv[rg], bcs));
        }
        __syncthreads();
        {
            int px = t >> 2, qd = t & 3;
            const ushort* src = sXn + px * 132 + qd * 32;
            ushort* dst = (ushort*)xn + (size_t)(m0 + px) * 128 + qd * 32;
#pragma unroll
            for (int g = 0; g < 4; ++g)
                *(short8*)(dst + g * 8) = *(const short8*)(src + g * 8);
        }
    }
}

// ---------------------------------------------------------------- dwconv3x3 + gate, v11
// LDS-staged halo: the block's 6x4-pixel halo (24 px x 1024B = 24KB) is staged with 24
// wave-wide global_load_lds (64 lanes x 16B each) -- replaces 144 scattered per-wave
// loads and their serialized waitcnt batches (v10: VALUBusy 54%, occ 33%, 43us,
// latency-bound). OOB halo pixels get a 1-instr wave-wide LDS zero-fill instead, so
// the compute body is branch-free and uniform for ALL blocks, with all 36 ds_read_b32
// at compile-time immediate offsets off one base reg (conflict-free: consecutive
// lanes -> consecutive dwords). Values bit-identical to v10 (OOB taps were zeros).
__global__ __launch_bounds__(256)
void dwgate_kernel(const __hip_bfloat16* __restrict__ t1, const float* __restrict__ dwt,
                   const float* __restrict__ dwb, __hip_bfloat16* __restrict__ tg)
{
    __shared__ __align__(16) char hsm[24576];          // 24 halo px x 1024B
    int t = threadIdx.x;
    int tc = t & 127;                  // channel pair (2 gate-ch) over all 256
    int tp = t >> 7;                   // 0..1 pixel column
    int lane = t & 63, wvid = t >> 6;
    int bx0 = blockIdx.x;              // 9216 = 2 * 48 * 96
    int bx = (bx0 & 7) * 1152 + (bx0 >> 3);          // XCD swizzle (9216 % 8 == 0)
    int b = bx / 4608; int tt = bx - b * 4608;
    int th = tt / 96, tw = tt - th * 96;
    int h0 = th * 4, w = tw * 2 + tp;
    int cu = tc * 2;                   // u-channel base 0..254

    // ---- stage halo: wave wvid handles pixels p = wvid*6 .. +6
    const short* t1s = (const short*)t1;
#pragma unroll
    for (int i = 0; i < 6; ++i) {
        int p = wvid * 6 + i;
        int r = p >> 2, c = p & 3;
        int hh = h0 - 1 + r, w2 = tw * 2 - 1 + c;
        char* dst = hsm + p * 1024;
        if (((unsigned)hh < 192u) & ((unsigned)w2 < 192u)) {   // wave-uniform
            const short* ga = t1s + (size_t)(b * HW + hh * 192 + w2) * 512 + lane * 8;
            __builtin_amdgcn_global_load_lds((const __attribute__((address_space(1))) void*)ga,
                                             (__attribute__((address_space(3))) void*)dst, 16, 0, 0);
        } else {
            *(f32x4*)(dst + lane * 16) = (f32x4){0.f, 0.f, 0.f, 0.f};
        }
    }

    // weights/bias load overlaps the staging latency
    f32x2 cwu[9], cwv[9];
#pragma unroll
    for (int tap = 0; tap < 9; ++tap) {
        cwu[tap] = *(const f32x2*)(dwt + tap * 512 + cu);
        cwv[tap] = *(const f32x2*)(dwt + tap * 512 + 256 + cu);
    }
    f32x2 bu = *(const f32x2*)(dwb + cu);
    f32x2 bv = *(const f32x2*)(dwb + 256 + cu);

    f32x2 au[4], av[4];
#pragma unroll
    for (int py = 0; py < 4; ++py) { au[py] = bu; av[py] = bv; }
    __syncthreads();

    const char* lbase = hsm + tp * 1024 + tc * 4;      // single base; taps are imm offsets
#pragma unroll
    for (int r = 0; r < 6; ++r) {
#pragma unroll
        for (int dxi = 0; dxi < 3; ++dxi) {
            int off = (r * 4 + dxi) * 1024;            // compile-time after unroll
            uint u2 = *(const uint*)(lbase + off);
            uint v2 = *(const uint*)(lbase + off + 512);
            f32x2 uf, vf;
            uf[0] = bf2f((ushort)(u2 & 0xffffu)); uf[1] = bf2f((ushort)(u2 >> 16));
            vf[0] = bf2f((ushort)(v2 & 0xffffu)); vf[1] = bf2f((ushort)(v2 >> 16));
#pragma unroll
            for (int py = 0; py < 4; ++py) {
                int dy = r - 1 - py;
                if (dy < -1 || dy > 1) continue;       // compile-time after unroll
                int tap = (dy + 1) * 3 + dxi;
#pragma unroll
                for (int e = 0; e < 2; ++e) {
                    au[py][e] = fmaf(cwu[tap][e], uf[e], au[py][e]);
                    av[py][e] = fmaf(cwv[tap][e], vf[e], av[py][e]);
                }
            }
        }
    }

#pragma unroll
    for (int py = 0; py < 4; ++py) {
        uint o = f2bf(au[py][0] * gelu_fast(av[py][0]))
               | (f2bf(au[py][1] * gelu_fast(av[py][1])) << 16);
        int gp = b * HW + (h0 + py) * 192 + w;
        *(uint*)((ushort*)tg + (size_t)gp * 256 + cu) = o;
    }
}

// ---------------------------------------------------------------- windowed attention (MFMA), v2
// Pad-free 16B-chunk XOR swizzle; 52752B LDS -> 3 blocks/CU; conflict-free fragment reads.
__device__ __forceinline__ int wpix(int wh, int ww, int m) {
    int ty = m >> 3, tx = m & 7;
    int hs = wh * 8 + ty + 4; if (hs >= 192) hs -= 192;
    int wsc = ww * 8 + tx + 4; if (wsc >= 192) wsc -= 192;
    return hs * 192 + wsc;
}
__device__ __forceinline__ int wreg(int wh, int ww, int m) {   // shift-mask region id
    int hr = wh * 8 + (m >> 3), wr = ww * 8 + (m & 7);
    return ((hr < 184) ? 0 : (hr < 188) ? 1 : 2) * 3 +
           ((wr < 184) ? 0 : (wr < 188) ? 1 : 2);
}

__global__ __launch_bounds__(256)
void attn_kernel(const __hip_bfloat16* __restrict__ qkv, const float* __restrict__ rpe,
                 __hip_bfloat16* __restrict__ attnout)
{
    __shared__ __align__(16) char smem[52752];
    int t = threadIdx.x;
    int lane = t & 63, head = t >> 6;
    int wh = blockIdx.x / 24, ww = blockIdx.x % 24;
    int b = blockIdx.y;
    int q = lane >> 4, r16 = lane & 15;

    float* rpe_s = (float*)(smem + 49152);
    for (int i = t; i < 900; i += 256) rpe_s[i] = rpe[i];

    char* Pbuf  = smem + head * 12288;   // [64 rows][8 chunks x 16B], chunk ^= row&7
    char* VTbuf = Pbuf + 8192;           // [32 d-rows][8 chunks x 16B], chunk ^= d&7
    const ushort* qkvu = (const ushort*)qkv;

    short8 aq[4], bk[4];
#pragma unroll
    for (int mt = 0; mt < 4; ++mt) {
        int pix = wpix(wh, ww, mt * 16 + r16);
        const ushort* rowp = qkvu + (size_t)(b * HW + pix) * 384 + head * 32 + q * 8;
        aq[mt] = *(const short8*)rowp;
        bk[mt] = *(const short8*)(rowp + 128);
    }
    {
        int pix = wpix(wh, ww, lane);
        const ushort* vp = qkvu + (size_t)(b * HW + pix) * 384 + 256 + head * 32;
        ushort* vt = (ushort*)VTbuf;
        int cpos = lane >> 3, within = lane & 7;
#pragma unroll
        for (int g = 0; g < 4; ++g) {
            short8 v8 = *(const short8*)(vp + g * 8);
#pragma unroll
            for (int e = 0; e < 8; ++e) {
                int d = g * 8 + e;
                vt[d * 64 + ((cpos ^ (d & 7)) * 8) + within] = (ushort)v8[e];
            }
        }
    }
    __syncthreads();

    f32x4 s[4][4];
#pragma unroll
    for (int mt = 0; mt < 4; ++mt)
#pragma unroll
        for (int nt = 0; nt < 4; ++nt) s[mt][nt] = (f32x4){0.f, 0.f, 0.f, 0.f};
#pragma unroll
    for (int mt = 0; mt < 4; ++mt)
#pragma unroll
        for (int nt = 0; nt < 4; ++nt)
            s[mt][nt] = __builtin_amdgcn_mfma_f32_16x16x32_bf16(aq[mt], bk[nt], s[mt][nt], 0, 0, 0);

    bool edge = (wh == 23) || (ww == 23);
    int tyj[4], txj[4], rgj[4];
#pragma unroll
    for (int nt = 0; nt < 4; ++nt) {
        int j = nt * 16 + r16;
        tyj[nt] = j >> 3; txj[nt] = j & 7;
        rgj[nt] = wreg(wh, ww, j);
    }
    float rinv[4][4];
#pragma unroll
    for (int mt = 0; mt < 4; ++mt) {
#pragma unroll
        for (int rg = 0; rg < 4; ++rg) {
            int i = mt * 16 + q * 4 + rg;
            int tyi = i >> 3, txi = i & 7;
            int rgi = edge ? wreg(wh, ww, i) : 0;
            float mx = -INFINITY;
#pragma unroll
            for (int nt = 0; nt < 4; ++nt) {
                float v = s[mt][nt][rg] * 0.17677669529663689f
                        + rpe_s[((tyi - tyj[nt] + 7) * 15 + (txi - txj[nt] + 7)) * 4 + head];
                if (edge && rgi != rgj[nt]) v = -INFINITY;
                s[mt][nt][rg] = v;
                mx = fmaxf(mx, v);
            }
            mx = fmaxf(mx, __shfl_xor(mx, 1));
            mx = fmaxf(mx, __shfl_xor(mx, 2));
            mx = fmaxf(mx, __shfl_xor(mx, 4));
            mx = fmaxf(mx, __shfl_xor(mx, 8));
            float sum = 0.f;
#pragma unroll
            for (int nt = 0; nt < 4; ++nt) {
                float e = __expf(s[mt][nt][rg] - mx);
                s[mt][nt][rg] = e;
                sum += e;
            }
            sum += __shfl_xor(sum, 1);
            sum += __shfl_xor(sum, 2);
            sum += __shfl_xor(sum, 4);
            sum += __shfl_xor(sum, 8);
            rinv[mt][rg] = 1.0f / sum;
        }
    }

    ushort* Pu = (ushort*)Pbuf;
#pragma unroll
    for (int mt = 0; mt < 4; ++mt)
#pragma unroll
        for (int rg = 0; rg < 4; ++rg) {
            int i = mt * 16 + q * 4 + rg;
            int sw = i & 7;
#pragma unroll
            for (int nt = 0; nt < 4; ++nt) {
                int j = nt * 16 + r16;
                Pu[i * 64 + ((j >> 3) ^ sw) * 8 + (j & 7)] = (ushort)f2bf(s[mt][nt][rg]);
            }
        }
    __syncthreads();   // fence: P writes visible before fragment reads

    f32x4 o[4][2];
#pragma unroll
    for (int mt = 0; mt < 4; ++mt) { o[mt][0] = (f32x4){0,0,0,0}; o[mt][1] = (f32x4){0,0,0,0}; }
    const ushort* Pus = (const ushort*)Pbuf;
    const ushort* Vus = (const ushort*)VTbuf;
#pragma unroll
    for (int ks = 0; ks < 2; ++ks) {
        int pc = ((ks * 4 + q) ^ (r16 & 7)) * 8;     // swizzled 16B chunk for this lane
        short8 ap[4];
#pragma unroll
        for (int mt = 0; mt < 4; ++mt)
            ap[mt] = *(const short8*)(Pus + (mt * 16 + r16) * 64 + pc);
        short8 bv[2];
#pragma unroll
        for (int nt = 0; nt < 2; ++nt)
            bv[nt] = *(const short8*)(Vus + (nt * 16 + r16) * 64 + pc);
#pragma unroll
        for (int mt = 0; mt < 4; ++mt)
#pragma unroll
            for (int nt = 0; nt < 2; ++nt)
                o[mt][nt] = __builtin_amdgcn_mfma_f32_16x16x32_bf16(ap[mt], bv[nt], o[mt][nt], 0, 0, 0);
    }
    __syncthreads();   // fence: P reads complete before Of float-overwrite (WAR)

    float* Of = (float*)Pbuf;                   // [64 rows][32 dwords], chunk ^= row&7
#pragma unroll
    for (int mt = 0; mt < 4; ++mt)
#pragma unroll
        for (int rg = 0; rg < 4; ++rg) {
            int i = mt * 16 + q * 4 + rg;
            int sw = i & 7;
            float sc = rinv[mt][rg];
            Of[i * 32 + (((r16 >> 2) ^ sw) * 4) + (r16 & 3)]       = o[mt][0][rg] * sc;
            Of[i * 32 + (((4 + (r16 >> 2)) ^ sw) * 4) + (r16 & 3)] = o[mt][1][rg] * sc;
        }
    __syncthreads();   // fence: Of writes before cross-lane reads
    {
        int pix = wpix(wh, ww, lane);
        ushort* ob = (ushort*)attnout + (size_t)(b * HW + pix) * 128 + head * 32;
        int sw = lane & 7;
#pragma unroll
        for (int g = 0; g < 4; ++g) {
            f32x4 lo = *(const f32x4*)&Of[lane * 32 + (((g * 2) ^ sw) * 4)];
            f32x4 hi = *(const f32x4*)&Of[lane * 32 + (((g * 2 + 1) ^ sw) * 4)];
            short8 o8;
#pragma unroll
            for (int e = 0; e < 4; ++e) {
                o8[e]     = (short)(ushort)f2bf(lo[e]);
                o8[e + 4] = (short)(ushort)f2bf(hi[e]);
            }
            *(short8*)(ob + g * 8) = o8;
        }
    }
}

// ---------------------------------------------------------------- launch
extern "C" void kernel_launch(void* const* d_in, const int* in_sizes, int n_in,
                              void* d_out, int out_size, void* d_ws, size_t ws_size,
                              hipStream_t stream)
{
    const float* x     = (const float*)d_in[0];
    const float* cg_s  = (const float*)d_in[1];
    const float* cg_b  = (const float*)d_in[2];
    const float* pw1_w = (const float*)d_in[3];
    const float* pw1_b = (const float*)d_in[4];
    const float* dw_w  = (const float*)d_in[5];
    const float* dw_b  = (const float*)d_in[6];
    const float* pw2_w = (const float*)d_in[7];
    const float* pw2_b = (const float*)d_in[8];
    const float* beta  = (const float*)d_in[9];
    const float* at_s  = (const float*)d_in[10];
    const float* at_b  = (const float*)d_in[11];
    const float* qkv_w = (const float*)d_in[12];
    const float* qkv_b = (const float*)d_in[13];
    const float* rpe   = (const float*)d_in[14];
    const float* proj_w= (const float*)d_in[15];
    const float* proj_b= (const float*)d_in[16];
    const float* alpha = (const float*)d_in[17];
    const float* ff_s  = (const float*)d_in[18];
    const float* ff_b  = (const float*)d_in[19];
    const float* fc1_w = (const float*)d_in[20];
    const float* fc1_b = (const float*)d_in[21];
    const float* fc2_w = (const float*)d_in[22];
    const float* fc2_b = (const float*)d_in[23];
    const float* gamma = (const float*)d_in[24];
    float* out = (float*)d_out;

    char* ws = (char*)d_ws;
    __hip_bfloat16* Xn    = (__hip_bfloat16*)ws;
    __hip_bfloat16* t1    = (__hip_bfloat16*)(ws + 18874368);
    __hip_bfloat16* qkvb  = t1;
    __hip_bfloat16* tg    = (__hip_bfloat16*)(ws + 94371840);
    __hip_bfloat16* attno = tg;
    char* wsw = ws + 132120576;
    ushort* w1b  = (ushort*)(wsw);             // 512*128
    ushort* w2b  = (ushort*)(wsw + 131072);    // 128*256
    ushort* wqb  = (ushort*)(wsw + 196608);    // 384*128
    ushort* wpb  = (ushort*)(wsw + 294912);    // 128*128
    ushort* wf1b = (ushort*)(wsw + 327680);    // 512*128 (paired u/v v2)
    ushort* wf2b = (ushort*)(wsw + 458752);    // 128*256
    float*  dwt  = (float*) (wsw + 524288);    // 9*512 fp32
    float*  bg1  = (float*) (wsw + 542720);    // 512 fp32 (paired fc1 bias v2)

    wconv_kernel<<<1044, 256, 0, stream>>>(pw1_w, pw2_w, qkv_w, proj_w, fc1_w, fc2_w, dw_w, fc1_b,
                                           w1b, w2b, wqb, wpb, wf1b, wf2b, dwt, bg1);

    // ---- stage 1: conv_gated_block (pw2 fuses residual + at-RMSNorm)
    rmsnorm_t_kernel<<<1152, 256, 0, stream>>>(x, cg_s, cg_b, Xn);
    gemm_kernel<128, 0><<<dim3(1152, 4), 256, 0, stream>>>(Xn, (__hip_bfloat16*)w1b, pw1_b, 512, t1);
    dwgate_kernel<<<9216, 256, 0, stream>>>(t1, dwt, dw_b, tg);
    gemm_n128_kernel<256, true><<<1152, 256, 0, stream>>>(tg, (__hip_bfloat16*)w2b, pw2_b,
                                                          x, out, beta, at_s, at_b, Xn);

    // ---- stage 2: window attention (proj fuses residual + ff-RMSNorm)
    gemm_kernel<128, 0><<<dim3(1152, 3), 256, 0, stream>>>(Xn, (__hip_bfloat16*)wqb, qkv_b, 384, qkvb);
    attn_kernel<<<dim3(576, 2), 256, 0, stream>>>(qkvb, rpe, attno);
    gemm_n128_kernel<128, true><<<1152, 256, 0, stream>>>(attno, (__hip_bfloat16*)wpb, proj_b,
                                                          out, out, alpha, ff_s, ff_b, Xn);

    // ---- stage 3: gated FFN (gate fused into fc1 GEMM epilogue, paired-v2)
    gemm_kernel<128, 2><<<dim3(1152, 4), 256, 0, stream>>>(Xn, (__hip_bfloat16*)wf1b, bg1, 512, tg);
    gemm_n128_kernel<256, false><<<1152, 256, 0, stream>>>(tg, (__hip_bfloat16*)wf2b, fc2_b,
                                                           out, out, gamma, nullptr, nullptr, nullptr);
}

// Round 9
// 336.376 us; speedup vs baseline: 1.0085x; 1.0085x over previous
//
#include <hip/hip_runtime.h>
#include <hip/hip_bf16.h>
#include <math.h>

#define HW   36864        // 192*192
#define BHW  73728        // 2*HW

typedef float f32x4 __attribute__((ext_vector_type(4)));
typedef float f32x2 __attribute__((ext_vector_type(2)));
typedef short short8 __attribute__((ext_vector_type(8)));

__device__ __forceinline__ unsigned f2bf(float f) {        // fp32 -> bf16 bits, RNE
    unsigned u = __float_as_uint(f);
    return (u + 0x7fffu + ((u >> 16) & 1u)) >> 16;
}
__device__ __forceinline__ float bf2f(unsigned short s) {  // bf16 bits -> fp32
    return __uint_as_float(((unsigned)s) << 16);
}
// tanh-approx gelu; <1e-3 abs dev from erf-gelu, ~7 instr vs ~25 for erff.
__device__ __forceinline__ float gelu_fast(float x) {
    float y = 1.5957691216057308f * fmaf(0.044715f * x * x, x, x);
    return x / (1.0f + __expf(-y));
}

// ---------------------------------------------------------------- weight prep
// fc1 weights/bias PAIRED v2: weight row j -> source channel (j>>5)*16 + (j&15),
// u/v = (j>>4)&1 -> u and v of one channel land in nt=0/1 of the same lane.
__global__ __launch_bounds__(256)
void wconv_kernel(const float* __restrict__ w1, const float* __restrict__ w2,
                  const float* __restrict__ wq, const float* __restrict__ wp,
                  const float* __restrict__ wf1, const float* __restrict__ wf2,
                  const float* __restrict__ dww, const float* __restrict__ fb1,
                  ushort* __restrict__ o1, ushort* __restrict__ o2, ushort* __restrict__ oq,
                  ushort* __restrict__ op, ushort* __restrict__ of1, ushort* __restrict__ of2,
                  float* __restrict__ dwt, float* __restrict__ bg)
{
    int i = blockIdx.x * 256 + threadIdx.x;
    if      (i <  65536) o1 [i         ] = (ushort)f2bf(w1 [i         ]);
    else if (i <  98304) o2 [i -  65536] = (ushort)f2bf(w2 [i -  65536]);
    else if (i < 147456) oq [i -  98304] = (ushort)f2bf(wq [i -  98304]);
    else if (i < 163840) op [i - 147456] = (ushort)f2bf(wp [i - 147456]);
    else if (i < 229376) {
        int j = i - 163840;            // paired fc1 v2: col=j>>7, k=j&127
        int col = j >> 7, k = j & 127;
        int src = ((col >> 4) & 1) * 256 + ((col >> 5) << 4) + (col & 15);
        of1[j] = (ushort)f2bf(wf1[(size_t)src * 128 + k]);
    }
    else if (i < 262144) of2[i - 229376] = (ushort)f2bf(wf2[i - 229376]);
    else if (i < 266752) {
        int j = i - 262144;            // j = tap*512 + c
        int tap = j >> 9, c = j & 511;
        dwt[j] = dww[c * 9 + tap];
    }
    else if (i < 267264) {
        int j = i - 266752;            // paired fc1 bias v2
        bg[j] = fb1[((j >> 4) & 1) * 256 + ((j >> 5) << 4) + (j & 15)];
    }
}

// ---------------------------------------------------------------- rmsnorm (NCHW fp32 -> pixel-major bf16)
// 64 pixels/block; the 4 waves split the 128-channel reduction (32 ch each).
__global__ __launch_bounds__(256)
void rmsnorm_t_kernel(const float* __restrict__ src, const float* __restrict__ s,
                      const float* __restrict__ bi, __hip_bfloat16* __restrict__ dst)
{
    __shared__ float sPar[4][64];
    __shared__ float sInv[64];
    int t = threadIdx.x, lane = t & 63, wv = t >> 6;
    int P = blockIdx.x * 64 + lane;                  // pixel id in [0, BHW)
    int b = P / HW, pp = P - b * HW;
    const float* xb = src + (size_t)b * 128 * HW + pp;
    float v[32];
    float ss = 0.f;
#pragma unroll
    for (int i = 0; i < 32; ++i) {
        float x = xb[(size_t)(wv * 32 + i) * HW];
        v[i] = x;
        ss = fmaf(x, x, ss);
    }
    sPar[wv][lane] = ss;
    __syncthreads();
    if (t < 64) {
        float tot = sPar[0][t] + sPar[1][t] + sPar[2][t] + sPar[3][t];
        sInv[t] = 1.0f / sqrtf(tot * 0.0078125f + 1e-6f);
    }
    __syncthreads();
    float inv = sInv[lane];
    unsigned* drow = (unsigned*)(dst + (size_t)P * 128) + wv * 16;
#pragma unroll
    for (int i = 0; i < 32; i += 2) {
        int c = wv * 32 + i;
        float v0 = fmaf(s[c]     * v[i],     inv, bi[c]);
        float v1 = fmaf(s[c + 1] * v[i + 1], inv, bi[c + 1]);
        drow[i >> 1] = f2bf(v0) | (f2bf(v1) << 16);
    }
}

// ---------------------------------------------------------------- MFMA GEMM, 64x128 tile
// v2: half-K 2-phase staging in 24KB LDS (was full-K 48KB). LDS ceiling 3->6 blocks/CU
// doubles the TLP hiding each vmcnt(0) stage-drain (round-6: occupancy 25%, latency-
// bound). 2 extra barriers per block; MFMA order unchanged -> bit-exact.
// MODE 0: store bf16 pixel-major (BHW,N). MODE 2: paired-v2 u/v in nt=0/1 -> u*gelu(v).
template<int K, int MODE>
__global__ __launch_bounds__(256)
void gemm_kernel(const __hip_bfloat16* __restrict__ Abf, const __hip_bfloat16* __restrict__ Wbf,
                 const float* __restrict__ bias, int N,
                 __hip_bfloat16* __restrict__ outb)
{
    constexpr int STEPS = K / 32;
    constexpr int PHASES = STEPS / 2;
    __shared__ __align__(16) short smem[(64 + 128) * K / 2];   // K=128: 24KB
    short* sA = smem;                 // [2][64 rows][32]
    short* sB = smem + 64 * (K / 2);  // [2][128 rows][32]

    const short* A = (const short*)Abf;
    const short* W = (const short*)Wbf;

    int t = threadIdx.x;
    int lane = t & 63, wv = t >> 6;
    int m0 = blockIdx.x * 64;
    int n0 = blockIdx.y * 128;
    int q = lane >> 4, r16 = lane & 15;
    int lr = lane >> 2, lk = lane & 3;
    int rowA = wv * 16 + lr;
    int kcA = lk ^ ((rowA >> 1) & 3);

    f32x4 acc[4][2];
    bool inited = false;

#pragma unroll
    for (int ph = 0; ph < PHASES; ++ph) {
        if (ph) __syncthreads();              // prev phase's ds_reads done before overwrite
#pragma unroll
        for (int sl = 0; sl < 2; ++sl) {      // stage 2 K-steps
            int gst = ph * 2 + sl;
            const short* ga = A + (size_t)(m0 + rowA) * K + gst * 32 + kcA * 8;
            __builtin_amdgcn_global_load_lds((const __attribute__((address_space(1))) void*)ga,
                                             (__attribute__((address_space(3))) void*)(sA + sl * 2048 + wv * 512), 16, 0, 0);
#pragma unroll
            for (int i = 0; i < 2; ++i) {
                int rb = wv * 32 + i * 16;
                int rowB = rb + lr;
                int kcB = lk ^ ((rowB >> 1) & 3);
                const short* gb = W + (size_t)(n0 + rowB) * K + gst * 32 + kcB * 8;
                __builtin_amdgcn_global_load_lds((const __attribute__((address_space(1))) void*)gb,
                                                 (__attribute__((address_space(3))) void*)(sB + sl * 4096 + rb * 32), 16, 0, 0);
            }
        }
        if (!inited) {                        // bias load overlaps first stage latency
            inited = true;
#pragma unroll
            for (int nt = 0; nt < 2; ++nt) {
                float bv = bias[n0 + wv * 32 + nt * 16 + r16];
#pragma unroll
                for (int mt = 0; mt < 4; ++mt) acc[mt][nt] = (f32x4){bv, bv, bv, bv};
            }
        }
        __syncthreads();

#pragma unroll
        for (int sl = 0; sl < 2; ++sl) {
            short8 af[4], bf[2];
#pragma unroll
            for (int mt = 0; mt < 4; ++mt) {
                int r = mt * 16 + r16;
                af[mt] = *(const short8*)(sA + sl * 2048 + (r * 4 + (q ^ ((r >> 1) & 3))) * 8);
            }
#pragma unroll
            for (int nt = 0; nt < 2; ++nt) {
                int r = wv * 32 + nt * 16 + r16;
                bf[nt] = *(const short8*)(sB + sl * 4096 + (r * 4 + (q ^ ((r >> 1) & 3))) * 8);
            }
#pragma unroll
            for (int mt = 0; mt < 4; ++mt)
#pragma unroll
                for (int nt = 0; nt < 2; ++nt)
                    acc[mt][nt] = __builtin_amdgcn_mfma_f32_16x16x32_bf16(af[mt], bf[nt], acc[mt][nt], 0, 0, 0);
        }
    }

    if constexpr (MODE == 0) {
        ushort* ob = (ushort*)outb;
#pragma unroll
        for (int mt = 0; mt < 4; ++mt) {
            int row0 = m0 + mt * 16 + q * 4;
#pragma unroll
            for (int nt = 0; nt < 2; ++nt) {
                int col = n0 + wv * 32 + nt * 16 + r16;
#pragma unroll
                for (int rg = 0; rg < 4; ++rg)
                    ob[(size_t)(row0 + rg) * N + col] = (ushort)f2bf(acc[mt][nt][rg]);
            }
        }
    } else {   // MODE 2, paired-v2: nt=0 holds u, nt=1 holds v of channel ch
        ushort* ob = (ushort*)outb;
        int ch = (n0 >> 1) + wv * 16 + r16;
#pragma unroll
        for (int mt = 0; mt < 4; ++mt) {
            int row0 = m0 + mt * 16 + q * 4;
#pragma unroll
            for (int rg = 0; rg < 4; ++rg) {
                float g = acc[mt][0][rg] * gelu_fast(acc[mt][1][rg]);
                ob[(size_t)(row0 + rg) * 256 + ch] = (ushort)f2bf(g);
            }
        }
    }
}

// ---------------------------------------------------------------- MFMA GEMM, N=128, 64-row tile
// Full-panel staging, processed in K/128 half-panels reusing 48KB of LDS.
template<int K, bool RMS>
__global__ __launch_bounds__(256, 3)
void gemm_n128_kernel(const __hip_bfloat16* __restrict__ Abf, const __hip_bfloat16* __restrict__ Wbf,
                      const float* __restrict__ bias,
                      const float* __restrict__ rsrc, float* __restrict__ rdst,
                      const float* __restrict__ scale,
                      const float* __restrict__ rms_s, const float* __restrict__ rms_b,
                      __hip_bfloat16* __restrict__ xn)
{
    constexpr int NH = K / 128;
    __shared__ __align__(16) char smem[49152];
    short* sA = (short*)smem;                 // [4][64 rows][32] = 16KB
    short* sB = sA + 8192;                    // [4][128 rows][32] = 32KB
    float* sEp = (float*)smem;                // [128 ch][68 px] = 34816 (overlays staging)
    float* sPar = (float*)(smem + 34816);     // RMS: [64 px][17]
    float* sInv = (float*)(smem + 39168);     // RMS: [64 px]

    const short* A = (const short*)Abf;
    const short* W = (const short*)Wbf;

    int t = threadIdx.x;
    int lane = t & 63, wv = t >> 6;
    int m0 = blockIdx.x * 64;
    int q = lane >> 4, r16 = lane & 15;

    f32x4 acc[4][2];
#pragma unroll
    for (int nt = 0; nt < 2; ++nt) {
        float bv = bias[wv * 32 + nt * 16 + r16];
#pragma unroll
        for (int mt = 0; mt < 4; ++mt) acc[mt][nt] = (f32x4){bv, bv, bv, bv};
    }

#pragma unroll
    for (int h = 0; h < NH; ++h) {
        if (h) __syncthreads();               // prev half's ds_reads done before overwrite
        {   // stage half panel (4 K-steps)
            int lr = lane >> 2, lk = lane & 3;
#pragma unroll
            for (int st = 0; st < 4; ++st) {
                int kk = h * 128 + st * 32;
                int rowA = wv * 16 + lr;
                int kcA = lk ^ ((rowA >> 1) & 3);
                const short* ga = A + (size_t)(m0 + rowA) * K + kk + kcA * 8;
                __builtin_amdgcn_global_load_lds((const __attribute__((address_space(1))) void*)ga,
                                                 (__attribute__((address_space(3))) void*)(sA + st * 2048 + wv * 512), 16, 0, 0);
#pragma unroll
                for (int i = 0; i < 2; ++i) {
                    int rb = wv * 32 + i * 16;
                    int rowB = rb + lr;
                    int kcB = lk ^ ((rowB >> 1) & 3);
                    const short* gb = W + (size_t)rowB * K + kk + kcB * 8;
                    __builtin_amdgcn_global_load_lds((const __attribute__((address_space(1))) void*)gb,
                                                     (__attribute__((address_space(3))) void*)(sB + st * 4096 + rb * 32), 16, 0, 0);
                }
            }
        }
        __syncthreads();

#pragma unroll
        for (int st = 0; st < 4; ++st) {
            short8 af[4], bf[2];
#pragma unroll
            for (int mt = 0; mt < 4; ++mt) {
                int r = mt * 16 + r16;
                af[mt] = *(const short8*)(sA + st * 2048 + (r * 4 + (q ^ ((r >> 1) & 3))) * 8);
            }
#pragma unroll
            for (int nt = 0; nt < 2; ++nt) {
                int r = wv * 32 + nt * 16 + r16;
                bf[nt] = *(const short8*)(sB + st * 4096 + (r * 4 + (q ^ ((r >> 1) & 3))) * 8);
            }
#pragma unroll
            for (int mt = 0; mt < 4; ++mt)
#pragma unroll
                for (int nt = 0; nt < 2; ++nt)
                    acc[mt][nt] = __builtin_amdgcn_mfma_f32_16x16x32_bf16(af[mt], bf[nt], acc[mt][nt], 0, 0, 0);
        }
    }
    __syncthreads();   // staging reads done before sEp overlay

    // single-pass epilogue: all 4 waves write their C fragments
#pragma unroll
    for (int mt = 0; mt < 4; ++mt)
#pragma unroll
        for (int nt = 0; nt < 2; ++nt) {
            int c = wv * 32 + nt * 16 + r16;
            int px = mt * 16 + q * 4;
#pragma unroll
            for (int rg = 0; rg < 4; ++rg)
                sEp[c * 68 + px + rg] = acc[mt][nt][rg];
        }
    __syncthreads();

    int c16 = t >> 4, l16 = t & 15;
    int p0 = m0 + l16 * 4;
    int b = p0 / HW, pp = p0 - b * HW;
    float sc = scale[0];
    f32x4 ov[8];
    f32x4 ps = (f32x4){0.f, 0.f, 0.f, 0.f};
#pragma unroll
    for (int i = 0; i < 8; ++i) {
        int c = c16 + i * 16;
        f32x4 v = *(const f32x4*)&sEp[c * 68 + l16 * 4];
        size_t gi = (size_t)(b * 128 + c) * HW + pp;
        f32x4 r = *(const f32x4*)&rsrc[gi];
        f32x4 o = r + sc * v;
        *(f32x4*)&rdst[gi] = o;
        if constexpr (RMS) {
            ov[i] = o;
#pragma unroll
            for (int rg = 0; rg < 4; ++rg) ps[rg] = fmaf(o[rg], o[rg], ps[rg]);
        }
    }
    if constexpr (RMS) {
#pragma unroll
        for (int rg = 0; rg < 4; ++rg) sPar[(l16 * 4 + rg) * 17 + c16] = ps[rg];
        __syncthreads();               // also fences sEp reads before sXn overlay
        if (t < 64) {
            float ssum = 0.f;
#pragma unroll
            for (int j = 0; j < 16; ++j) ssum += sPar[t * 17 + j];
            sInv[t] = 1.0f / sqrtf(ssum * 0.0078125f + 1e-6f);
        }
        __syncthreads();
        float iv[4];
#pragma unroll
        for (int rg = 0; rg < 4; ++rg) iv[rg] = sInv[l16 * 4 + rg];
        ushort* sXn = (ushort*)smem;   // overlay dead sEp: [64 px][132 ch-pad]
#pragma unroll
        for (int i = 0; i < 8; ++i) {
            int c = c16 + i * 16;
            float scs = rms_s[c], bcs = rms_b[c];
#pragma unroll
            for (int rg = 0; rg < 4; ++rg)
                sXn[(l16 * 4 + rg) * 132 + c] = (ushort)f2bf(fmaf(scs * ov[i][rg], iv[rg], bcs));
        }
        __syncthreads();
        {
            int px = t >> 2, qd = t & 3;
            const ushort* src = sXn + px * 132 + qd * 32;
            ushort* dst = (ushort*)xn + (size_t)(m0 + px) * 128 + qd * 32;
#pragma unroll
            for (int g = 0; g < 4; ++g)
                *(short8*)(dst + g * 8) = *(const short8*)(src + g * 8);
        }
    }
}

// ---------------------------------------------------------------- dwconv3x3 + gate, v12
// v11 structure (LDS-staged halo) + VALU cut: round-8 showed VALUBusy 70% -> the
// kernel is VALU-throughput-limited. (a) bf16x2 dword unpack as lo=u<<16 /
// hi=u&0xffff0000 (2 ops vs 4, bit-identical); (b) __builtin_elementwise_fma on
// f32x2 -> v_pk_fma_f32 (2 FMAs/instr, IEEE fma per element, bit-identical).
__global__ __launch_bounds__(256)
void dwgate_kernel(const __hip_bfloat16* __restrict__ t1, const float* __restrict__ dwt,
                   const float* __restrict__ dwb, __hip_bfloat16* __restrict__ tg)
{
    __shared__ __align__(16) char hsm[24576];          // 24 halo px x 1024B
    int t = threadIdx.x;
    int tc = t & 127;                  // channel pair (2 gate-ch) over all 256
    int tp = t >> 7;                   // 0..1 pixel column
    int lane = t & 63, wvid = t >> 6;
    int bx0 = blockIdx.x;              // 9216 = 2 * 48 * 96
    int bx = (bx0 & 7) * 1152 + (bx0 >> 3);          // XCD swizzle (9216 % 8 == 0)
    int b = bx / 4608; int tt = bx - b * 4608;
    int th = tt / 96, tw = tt - th * 96;
    int h0 = th * 4, w = tw * 2 + tp;
    int cu = tc * 2;                   // u-channel base 0..254

    // ---- stage halo: wave wvid handles pixels p = wvid*6 .. +6
    const short* t1s = (const short*)t1;
#pragma unroll
    for (int i = 0; i < 6; ++i) {
        int p = wvid * 6 + i;
        int r = p >> 2, c = p & 3;
        int hh = h0 - 1 + r, w2 = tw * 2 - 1 + c;
        char* dst = hsm + p * 1024;
        if (((unsigned)hh < 192u) & ((unsigned)w2 < 192u)) {   // wave-uniform
            const short* ga = t1s + (size_t)(b * HW + hh * 192 + w2) * 512 + lane * 8;
            __builtin_amdgcn_global_load_lds((const __attribute__((address_space(1))) void*)ga,
                                             (__attribute__((address_space(3))) void*)dst, 16, 0, 0);
        } else {
            *(f32x4*)(dst + lane * 16) = (f32x4){0.f, 0.f, 0.f, 0.f};
        }
    }

    // weights/bias load overlaps the staging latency
    f32x2 cwu[9], cwv[9];
#pragma unroll
    for (int tap = 0; tap < 9; ++tap) {
        cwu[tap] = *(const f32x2*)(dwt + tap * 512 + cu);
        cwv[tap] = *(const f32x2*)(dwt + tap * 512 + 256 + cu);
    }
    f32x2 bu = *(const f32x2*)(dwb + cu);
    f32x2 bv = *(const f32x2*)(dwb + 256 + cu);

    f32x2 au[4], av[4];
#pragma unroll
    for (int py = 0; py < 4; ++py) { au[py] = bu; av[py] = bv; }
    __syncthreads();

    const char* lbase = hsm + tp * 1024 + tc * 4;      // single base; taps are imm offsets
#pragma unroll
    for (int r = 0; r < 6; ++r) {
#pragma unroll
        for (int dxi = 0; dxi < 3; ++dxi) {
            int off = (r * 4 + dxi) * 1024;            // compile-time after unroll
            uint u2 = *(const uint*)(lbase + off);
            uint v2 = *(const uint*)(lbase + off + 512);
            f32x2 uf, vf;
            uf[0] = __uint_as_float(u2 << 16);         // ch0: low bf16 (bit-identical)
            uf[1] = __uint_as_float(u2 & 0xffff0000u); // ch1: high bf16
            vf[0] = __uint_as_float(v2 << 16);
            vf[1] = __uint_as_float(v2 & 0xffff0000u);
#pragma unroll
            for (int py = 0; py < 4; ++py) {
                int dy = r - 1 - py;
                if (dy < -1 || dy > 1) continue;       // compile-time after unroll
                int tap = (dy + 1) * 3 + dxi;
                au[py] = __builtin_elementwise_fma(cwu[tap], uf, au[py]);
                av[py] = __builtin_elementwise_fma(cwv[tap], vf, av[py]);
            }
        }
    }

#pragma unroll
    for (int py = 0; py < 4; ++py) {
        uint o = f2bf(au[py][0] * gelu_fast(av[py][0]))
               | (f2bf(au[py][1] * gelu_fast(av[py][1])) << 16);
        int gp = b * HW + (h0 + py) * 192 + w;
        *(uint*)((ushort*)tg + (size_t)gp * 256 + cu) = o;
    }
}

// ---------------------------------------------------------------- windowed attention (MFMA), v2
// Pad-free 16B-chunk XOR swizzle; 52752B LDS -> 3 blocks/CU; conflict-free fragment reads.
__device__ __forceinline__ int wpix(int wh, int ww, int m) {
    int ty = m >> 3, tx = m & 7;
    int hs = wh * 8 + ty + 4; if (hs >= 192) hs -= 192;
    int wsc = ww * 8 + tx + 4; if (wsc >= 192) wsc -= 192;
    return hs * 192 + wsc;
}
__device__ __forceinline__ int wreg(int wh, int ww, int m) {   // shift-mask region id
    int hr = wh * 8 + (m >> 3), wr = ww * 8 + (m & 7);
    return ((hr < 184) ? 0 : (hr < 188) ? 1 : 2) * 3 +
           ((wr < 184) ? 0 : (wr < 188) ? 1 : 2);
}

__global__ __launch_bounds__(256)
void attn_kernel(const __hip_bfloat16* __restrict__ qkv, const float* __restrict__ rpe,
                 __hip_bfloat16* __restrict__ attnout)
{
    __shared__ __align__(16) char smem[52752];
    int t = threadIdx.x;
    int lane = t & 63, head = t >> 6;
    int wh = blockIdx.x / 24, ww = blockIdx.x % 24;
    int b = blockIdx.y;
    int q = lane >> 4, r16 = lane & 15;

    float* rpe_s = (float*)(smem + 49152);
    for (int i = t; i < 900; i += 256) rpe_s[i] = rpe[i];

    char* Pbuf  = smem + head * 12288;   // [64 rows][8 chunks x 16B], chunk ^= row&7
    char* VTbuf = Pbuf + 8192;           // [32 d-rows][8 chunks x 16B], chunk ^= d&7
    const ushort* qkvu = (const ushort*)qkv;

    short8 aq[4], bk[4];
#pragma unroll
    for (int mt = 0; mt < 4; ++mt) {
        int pix = wpix(wh, ww, mt * 16 + r16);
        const ushort* rowp = qkvu + (size_t)(b * HW + pix) * 384 + head * 32 + q * 8;
        aq[mt] = *(const short8*)rowp;
        bk[mt] = *(const short8*)(rowp + 128);
    }
    {
        int pix = wpix(wh, ww, lane);
        const ushort* vp = qkvu + (size_t)(b * HW + pix) * 384 + 256 + head * 32;
        ushort* vt = (ushort*)VTbuf;
        int cpos = lane >> 3, within = lane & 7;
#pragma unroll
        for (int g = 0; g < 4; ++g) {
            short8 v8 = *(const short8*)(vp + g * 8);
#pragma unroll
            for (int e = 0; e < 8; ++e) {
                int d = g * 8 + e;
                vt[d * 64 + ((cpos ^ (d & 7)) * 8) + within] = (ushort)v8[e];
            }
        }
    }
    __syncthreads();

    f32x4 s[4][4];
#pragma unroll
    for (int mt = 0; mt < 4; ++mt)
#pragma unroll
        for (int nt = 0; nt < 4; ++nt) s[mt][nt] = (f32x4){0.f, 0.f, 0.f, 0.f};
#pragma unroll
    for (int mt = 0; mt < 4; ++mt)
#pragma unroll
        for (int nt = 0; nt < 4; ++nt)
            s[mt][nt] = __builtin_amdgcn_mfma_f32_16x16x32_bf16(aq[mt], bk[nt], s[mt][nt], 0, 0, 0);

    bool edge = (wh == 23) || (ww == 23);
    int tyj[4], txj[4], rgj[4];
#pragma unroll
    for (int nt = 0; nt < 4; ++nt) {
        int j = nt * 16 + r16;
        tyj[nt] = j >> 3; txj[nt] = j & 7;
        rgj[nt] = wreg(wh, ww, j);
    }
    float rinv[4][4];
#pragma unroll
    for (int mt = 0; mt < 4; ++mt) {
#pragma unroll
        for (int rg = 0; rg < 4; ++rg) {
            int i = mt * 16 + q * 4 + rg;
            int tyi = i >> 3, txi = i & 7;
            int rgi = edge ? wreg(wh, ww, i) : 0;
            float mx = -INFINITY;
#pragma unroll
            for (int nt = 0; nt < 4; ++nt) {
                float v = s[mt][nt][rg] * 0.17677669529663689f
                        + rpe_s[((tyi - tyj[nt] + 7) * 15 + (txi - txj[nt] + 7)) * 4 + head];
                if (edge && rgi != rgj[nt]) v = -INFINITY;
                s[mt][nt][rg] = v;
                mx = fmaxf(mx, v);
            }
            mx = fmaxf(mx, __shfl_xor(mx, 1));
            mx = fmaxf(mx, __shfl_xor(mx, 2));
            mx = fmaxf(mx, __shfl_xor(mx, 4));
            mx = fmaxf(mx, __shfl_xor(mx, 8));
            float sum = 0.f;
#pragma unroll
            for (int nt = 0; nt < 4; ++nt) {
                float e = __expf(s[mt][nt][rg] - mx);
                s[mt][nt][rg] = e;
                sum += e;
            }
            sum += __shfl_xor(sum, 1);
            sum += __shfl_xor(sum, 2);
            sum += __shfl_xor(sum, 4);
            sum += __shfl_xor(sum, 8);
            rinv[mt][rg] = 1.0f / sum;
        }
    }

    ushort* Pu = (ushort*)Pbuf;
#pragma unroll
    for (int mt = 0; mt < 4; ++mt)
#pragma unroll
        for (int rg = 0; rg < 4; ++rg) {
            int i = mt * 16 + q * 4 + rg;
            int sw = i & 7;
#pragma unroll
            for (int nt = 0; nt < 4; ++nt) {
                int j = nt * 16 + r16;
                Pu[i * 64 + ((j >> 3) ^ sw) * 8 + (j & 7)] = (ushort)f2bf(s[mt][nt][rg]);
            }
        }
    __syncthreads();   // fence: P writes visible before fragment reads

    f32x4 o[4][2];
#pragma unroll
    for (int mt = 0; mt < 4; ++mt) { o[mt][0] = (f32x4){0,0,0,0}; o[mt][1] = (f32x4){0,0,0,0}; }
    const ushort* Pus = (const ushort*)Pbuf;
    const ushort* Vus = (const ushort*)VTbuf;
#pragma unroll
    for (int ks = 0; ks < 2; ++ks) {
        int pc = ((ks * 4 + q) ^ (r16 & 7)) * 8;     // swizzled 16B chunk for this lane
        short8 ap[4];
#pragma unroll
        for (int mt = 0; mt < 4; ++mt)
            ap[mt] = *(const short8*)(Pus + (mt * 16 + r16) * 64 + pc);
        short8 bv[2];
#pragma unroll
        for (int nt = 0; nt < 2; ++nt)
            bv[nt] = *(const short8*)(Vus + (nt * 16 + r16) * 64 + pc);
#pragma unroll
        for (int mt = 0; mt < 4; ++mt)
#pragma unroll
            for (int nt = 0; nt < 2; ++nt)
                o[mt][nt] = __builtin_amdgcn_mfma_f32_16x16x32_bf16(ap[mt], bv[nt], o[mt][nt], 0, 0, 0);
    }
    __syncthreads();   // fence: P reads complete before Of float-overwrite (WAR)

    float* Of = (float*)Pbuf;                   // [64 rows][32 dwords], chunk ^= row&7
#pragma unroll
    for (int mt = 0; mt < 4; ++mt)
#pragma unroll
        for (int rg = 0; rg < 4; ++rg) {
            int i = mt * 16 + q * 4 + rg;
            int sw = i & 7;
            float sc = rinv[mt][rg];
            Of[i * 32 + (((r16 >> 2) ^ sw) * 4) + (r16 & 3)]       = o[mt][0][rg] * sc;
            Of[i * 32 + (((4 + (r16 >> 2)) ^ sw) * 4) + (r16 & 3)] = o[mt][1][rg] * sc;
        }
    __syncthreads();   // fence: Of writes before cross-lane reads
    {
        int pix = wpix(wh, ww, lane);
        ushort* ob = (ushort*)attnout + (size_t)(b * HW + pix) * 128 + head * 32;
        int sw = lane & 7;
#pragma unroll
        for (int g = 0; g < 4; ++g) {
            f32x4 lo = *(const f32x4*)&Of[lane * 32 + (((g * 2) ^ sw) * 4)];
            f32x4 hi = *(const f32x4*)&Of[lane * 32 + (((g * 2 + 1) ^ sw) * 4)];
            short8 o8;
#pragma unroll
            for (int e = 0; e < 4; ++e) {
                o8[e]     = (short)(ushort)f2bf(lo[e]);
                o8[e + 4] = (short)(ushort)f2bf(hi[e]);
            }
            *(short8*)(ob + g * 8) = o8;
        }
    }
}

// ---------------------------------------------------------------- launch
extern "C" void kernel_launch(void* const* d_in, const int* in_sizes, int n_in,
                              void* d_out, int out_size, void* d_ws, size_t ws_size,
                              hipStream_t stream)
{
    const float* x     = (const float*)d_in[0];
    const float* cg_s  = (const float*)d_in[1];
    const float* cg_b  = (const float*)d_in[2];
    const float* pw1_w = (const float*)d_in[3];
    const float* pw1_b = (const float*)d_in[4];
    const float* dw_w  = (const float*)d_in[5];
    const float* dw_b  = (const float*)d_in[6];
    const float* pw2_w = (const float*)d_in[7];
    const float* pw2_b = (const float*)d_in[8];
    const float* beta  = (const float*)d_in[9];
    const float* at_s  = (const float*)d_in[10];
    const float* at_b  = (const float*)d_in[11];
    const float* qkv_w = (const float*)d_in[12];
    const float* qkv_b = (const float*)d_in[13];
    const float* rpe   = (const float*)d_in[14];
    const float* proj_w= (const float*)d_in[15];
    const float* proj_b= (const float*)d_in[16];
    const float* alpha = (const float*)d_in[17];
    const float* ff_s  = (const float*)d_in[18];
    const float* ff_b  = (const float*)d_in[19];
    const float* fc1_w = (const float*)d_in[20];
    const float* fc1_b = (const float*)d_in[21];
    const float* fc2_w = (const float*)d_in[22];
    const float* fc2_b = (const float*)d_in[23];
    const float* gamma = (const float*)d_in[24];
    float* out = (float*)d_out;

    char* ws = (char*)d_ws;
    __hip_bfloat16* Xn    = (__hip_bfloat16*)ws;
    __hip_bfloat16* t1    = (__hip_bfloat16*)(ws + 18874368);
    __hip_bfloat16* qkvb  = t1;
    __hip_bfloat16* tg    = (__hip_bfloat16*)(ws + 94371840);
    __hip_bfloat16* attno = tg;
    char* wsw = ws + 132120576;
    ushort* w1b  = (ushort*)(wsw);             // 512*128
    ushort* w2b  = (ushort*)(wsw + 131072);    // 128*256
    ushort* wqb  = (ushort*)(wsw + 196608);    // 384*128
    ushort* wpb  = (ushort*)(wsw + 294912);    // 128*128
    ushort* wf1b = (ushort*)(wsw + 327680);    // 512*128 (paired u/v v2)
    ushort* wf2b = (ushort*)(wsw + 458752);    // 128*256
    float*  dwt  = (float*) (wsw + 524288);    // 9*512 fp32
    float*  bg1  = (float*) (wsw + 542720);    // 512 fp32 (paired fc1 bias v2)

    wconv_kernel<<<1044, 256, 0, stream>>>(pw1_w, pw2_w, qkv_w, proj_w, fc1_w, fc2_w, dw_w, fc1_b,
                                           w1b, w2b, wqb, wpb, wf1b, wf2b, dwt, bg1);

    // ---- stage 1: conv_gated_block (pw2 fuses residual + at-RMSNorm)
    rmsnorm_t_kernel<<<1152, 256, 0, stream>>>(x, cg_s, cg_b, Xn);
    gemm_kernel<128, 0><<<dim3(1152, 4), 256, 0, stream>>>(Xn, (__hip_bfloat16*)w1b, pw1_b, 512, t1);
    dwgate_kernel<<<9216, 256, 0, stream>>>(t1, dwt, dw_b, tg);
    gemm_n128_kernel<256, true><<<1152, 256, 0, stream>>>(tg, (__hip_bfloat16*)w2b, pw2_b,
                                                          x, out, beta, at_s, at_b, Xn);

    // ---- stage 2: window attention (proj fuses residual + ff-RMSNorm)
    gemm_kernel<128, 0><<<dim3(1152, 3), 256, 0, stream>>>(Xn, (__hip_bfloat16*)wqb, qkv_b, 384, qkvb);
    attn_kernel<<<dim3(576, 2), 256, 0, stream>>>(qkvb, rpe, attno);
    gemm_n128_kernel<128, true><<<1152, 256, 0, stream>>>(attno, (__hip_bfloat16*)wpb, proj_b,
                                                          out, out, alpha, ff_s, ff_b, Xn);

    // ---- stage 3: gated FFN (gate fused into fc1 GEMM epilogue, paired-v2)
    gemm_kernel<128, 2><<<dim3(1152, 4), 256, 0, stream>>>(Xn, (__hip_bfloat16*)wf1b, bg1, 512, tg);
    gemm_n128_kernel<256, false><<<1152, 256, 0, stream>>>(tg, (__hip_bfloat16*)wf2b, fc2_b,
                                                           out, out, gamma, nullptr, nullptr, nullptr);
}